// Round 1
// baseline (560.440 us; speedup 1.0000x reference)
//
#include <hip/hip_runtime.h>
#include <hip/hip_fp16.h>
#include <cstdint>
#include <cstddef>

typedef _Float16 f16x8 __attribute__((ext_vector_type(8)));
typedef _Float16 f16x4 __attribute__((ext_vector_type(4)));
typedef float    f32x4 __attribute__((ext_vector_type(4)));

#define GPTR(p) ((const __attribute__((address_space(1))) void*)(p))
#define SPTR(p) ((__attribute__((address_space(3))) void*)(p))

// ---------------------------------------------------------------------------
// Transpose + cast fp32 -> fp16 : W (R x C) row-major -> Wt (C x R) row-major
// ---------------------------------------------------------------------------
__global__ void transpose_cast_kernel(const float* __restrict__ W,
                                      _Float16* __restrict__ Wt,
                                      int R, int C) {
  __shared__ float tile[32][33];
  const int c  = blockIdx.x * 32 + threadIdx.x;
  const int r0 = blockIdx.y * 32;
  for (int i = threadIdx.y; i < 32; i += 8)
    tile[i][threadIdx.x] = W[(size_t)(r0 + i) * C + c];
  __syncthreads();
  const int out_c = r0 + threadIdx.x;   // new col = old row
  const int oc0   = blockIdx.x * 32;    // new row = old col
  for (int i = threadIdx.y; i < 32; i += 8)
    Wt[(size_t)(oc0 + i) * R + out_c] = (_Float16)tile[threadIdx.x][i];
}

// ---------------------------------------------------------------------------
// GEMM: C(MxN) = A(MxK fp32) @ Bt(NxK fp16)^T, + bias, epilogue by MODE.
// MODE 0: C = elu(acc + bias)          (feature maps)
// MODE 1: C = scale[row]*(acc + bias)  (V projection, fused output scaling)
// Block: 128x128 tile, BK=32, 256 threads (4 waves, 2x2), 16x16x32 f16 MFMA.
// ---------------------------------------------------------------------------
template <int MODE>
__global__ __launch_bounds__(256) void gemm_f16(
    const float* __restrict__ A,      // M x K (fp32, row-major)
    const _Float16* __restrict__ Bt,  // N x K (fp16, row-major) = B^T
    const float* __restrict__ bias,   // N
    const float* __restrict__ scale,  // M (MODE 1 only)
    float* __restrict__ C,            // M x N
    int K, int N) {
  constexpr int BK  = 32;
  constexpr int AST = 40;  // As row stride in halves (80 B, breaks bank conflicts)
  __shared__ __align__(16) _Float16 As[128 * AST];
  __shared__ __align__(16) _Float16 Bs[128 * BK];  // contiguous: chunk c at byte c*16

  const int tid  = threadIdx.x;
  const int lane = tid & 63;
  const int wave = tid >> 6;
  const int quad = lane >> 4;
  const int r    = lane & 15;
  const int wm   = wave >> 1;  // wave row (0..1)
  const int wn   = wave & 1;   // wave col (0..1)
  const int m0   = blockIdx.y * 128;
  const int n0   = blockIdx.x * 128;

  f32x4 acc[4][4] = {};

  const int kIters = K / BK;
  for (int kk = 0; kk < kIters; ++kk) {
    const int k0 = kk * BK;
    __syncthreads();
    // ---- stage A tile (128 x 32): fp32 global -> cvt -> fp16 LDS ----
#pragma unroll
    for (int i = 0; i < 4; ++i) {
      const int cchunk = tid + i * 256;  // 0..1023 float4-chunks
      const int row = cchunk >> 3;       // 8 chunks per row of 32 floats
      const int k4  = cchunk & 7;
      const float4 v =
          *(const float4*)(A + (size_t)(m0 + row) * K + k0 + k4 * 4);
      f16x4 h;
      h[0] = (_Float16)v.x; h[1] = (_Float16)v.y;
      h[2] = (_Float16)v.z; h[3] = (_Float16)v.w;
      *(f16x4*)(&As[row * AST + k4 * 4]) = h;
    }
    // ---- stage B tile (128 x 32 fp16) via async global->LDS, 16B/lane ----
#pragma unroll
    for (int j2 = 0; j2 < 2; ++j2) {
      const int cbase = wave * 128 + j2 * 64;  // wave-uniform chunk base
      const int chunk = cbase + lane;
      const int nrow  = chunk >> 2;  // 4 chunks (64B) per row of 32 halves
      const int kc    = chunk & 3;
      const _Float16* gp = Bt + (size_t)(n0 + nrow) * K + k0 + kc * 8;
      __builtin_amdgcn_global_load_lds(GPTR(gp), SPTR(&Bs[cbase * 8]), 16, 0, 0);
    }
    __syncthreads();
    // ---- compute: 4x4 subtiles of 16x16, one x32 MFMA each ----
    f16x8 af[4], bf[4];
#pragma unroll
    for (int i = 0; i < 4; ++i)
      af[i] = *(const f16x8*)(&As[(wm * 64 + i * 16 + r) * AST + quad * 8]);
#pragma unroll
    for (int j = 0; j < 4; ++j)
      bf[j] = *(const f16x8*)(&Bs[(wn * 64 + j * 16 + r) * BK + quad * 8]);
#pragma unroll
    for (int i = 0; i < 4; ++i)
#pragma unroll
      for (int j = 0; j < 4; ++j)
        acc[i][j] =
            __builtin_amdgcn_mfma_f32_16x16x32_f16(af[i], bf[j], acc[i][j], 0, 0, 0);
  }

  // ---- epilogue: C/D layout col=lane&15, row=quad*4+reg ----
#pragma unroll
  for (int i = 0; i < 4; ++i) {
#pragma unroll
    for (int j = 0; j < 4; ++j) {
      const int col = n0 + wn * 64 + j * 16 + r;
      const float b = bias[col];
#pragma unroll
      for (int reg = 0; reg < 4; ++reg) {
        const int row = m0 + wm * 64 + i * 16 + quad * 4 + reg;
        float v = acc[i][j][reg] + b;
        if (MODE == 0) {
          v = v > 0.f ? v : (expf(v) - 1.f);  // ELU (no +1), matching reference
        } else {
          v = v * scale[row];
        }
        C[(size_t)row * N + col] = v;
      }
    }
  }
}

// ---------------------------------------------------------------------------
// Per-row reduction: scale[b] = (Qf[b].Kf[b]) / (sum(Qf[b])*sum(Kf[b]) + eps)
// F = 1024, one block (256 thr) per row, each thread one float4.
// ---------------------------------------------------------------------------
__global__ void reduce_scale_kernel(const float* __restrict__ Qf,
                                    const float* __restrict__ Kf,
                                    float* __restrict__ scale) {
  const int b = blockIdx.x;
  const int t = threadIdx.x;
  const float4 q = ((const float4*)(Qf + (size_t)b * 1024))[t];
  const float4 k = ((const float4*)(Kf + (size_t)b * 1024))[t];
  float qk = q.x * k.x + q.y * k.y + q.z * k.z + q.w * k.w;
  float sq = q.x + q.y + q.z + q.w;
  float sk = k.x + k.y + k.z + k.w;
#pragma unroll
  for (int off = 32; off > 0; off >>= 1) {
    qk += __shfl_down(qk, off, 64);
    sq += __shfl_down(sq, off, 64);
    sk += __shfl_down(sk, off, 64);
  }
  __shared__ float buf[3][4];
  const int lane = t & 63, wv = t >> 6;
  if (lane == 0) { buf[0][wv] = qk; buf[1][wv] = sq; buf[2][wv] = sk; }
  __syncthreads();
  if (t == 0) {
    const float QK = buf[0][0] + buf[0][1] + buf[0][2] + buf[0][3];
    const float SQ = buf[1][0] + buf[1][1] + buf[1][2] + buf[1][3];
    const float SK = buf[2][0] + buf[2][1] + buf[2][2] + buf[2][3];
    scale[b] = QK / (SQ * SK + 1e-6f);
  }
}

// ---------------------------------------------------------------------------
extern "C" void kernel_launch(void* const* d_in, const int* in_sizes, int n_in,
                              void* d_out, int out_size, void* d_ws,
                              size_t ws_size, hipStream_t stream) {
  const float* Q  = (const float*)d_in[0];
  const float* K_ = (const float*)d_in[1];
  const float* V  = (const float*)d_in[2];
  const float* Wq = (const float*)d_in[3];
  const float* bq = (const float*)d_in[4];
  const float* Wk = (const float*)d_in[5];
  const float* bk = (const float*)d_in[6];
  const float* Wv = (const float*)d_in[7];
  const float* bv = (const float*)d_in[8];
  float* out = (float*)d_out;

  const int B = 8192, D = 2048, F = 1024;

  // ws layout (fp16 transposed weights + row scales): ~16.8 MB total
  char* ws = (char*)d_ws;
  _Float16* WqT = (_Float16*)(ws);                            // F x D, 4 MB
  _Float16* WkT = (_Float16*)(ws + (size_t)4 * 1024 * 1024);  // F x D, 4 MB
  _Float16* WvT = (_Float16*)(ws + (size_t)8 * 1024 * 1024);  // D x D, 8 MB
  float* scale  = (float*)(ws + (size_t)16 * 1024 * 1024);    // B floats

  // Qf/Kf live in d_out as scratch (B*F*2 floats == out_size exactly);
  // final GEMM fully overwrites d_out afterwards.
  float* Qf = out;
  float* Kf = out + (size_t)B * F;

  dim3 tb(32, 8);
  transpose_cast_kernel<<<dim3(F / 32, D / 32), tb, 0, stream>>>(Wq, WqT, D, F);
  transpose_cast_kernel<<<dim3(F / 32, D / 32), tb, 0, stream>>>(Wk, WkT, D, F);
  transpose_cast_kernel<<<dim3(D / 32, D / 32), tb, 0, stream>>>(Wv, WvT, D, D);

  gemm_f16<0><<<dim3(F / 128, B / 128), 256, 0, stream>>>(Q,  WqT, bq, nullptr, Qf, D, F);
  gemm_f16<0><<<dim3(F / 128, B / 128), 256, 0, stream>>>(K_, WkT, bk, nullptr, Kf, D, F);
  reduce_scale_kernel<<<B, 256, 0, stream>>>(Qf, Kf, scale);
  gemm_f16<1><<<dim3(D / 128, B / 128), 256, 0, stream>>>(V,  WvT, bv, scale, out, D, D);
}

// Round 2
// 441.101 us; speedup vs baseline: 1.2705x; 1.2705x over previous
//
#include <hip/hip_runtime.h>
#include <hip/hip_fp16.h>
#include <cstdint>
#include <cstddef>

typedef _Float16 f16x8 __attribute__((ext_vector_type(8)));
typedef _Float16 f16x4 __attribute__((ext_vector_type(4)));
typedef float    f32x4 __attribute__((ext_vector_type(4)));

#define GPTR(p) ((const __attribute__((address_space(1))) void*)(p))
#define SPTR(p) ((__attribute__((address_space(3))) void*)(p))

// ---------------------------------------------------------------------------
// Transpose + cast fp32 -> fp16 : W (R x C) row-major -> Wt (C x R) row-major
// ---------------------------------------------------------------------------
__global__ void transpose_cast_kernel(const float* __restrict__ W,
                                      _Float16* __restrict__ Wt,
                                      int R, int C) {
  __shared__ float tile[32][33];
  const int c  = blockIdx.x * 32 + threadIdx.x;
  const int r0 = blockIdx.y * 32;
  for (int i = threadIdx.y; i < 32; i += 8)
    tile[i][threadIdx.x] = W[(size_t)(r0 + i) * C + c];
  __syncthreads();
  const int out_c = r0 + threadIdx.x;   // new col = old row
  const int oc0   = blockIdx.x * 32;    // new row = old col
  for (int i = threadIdx.y; i < 32; i += 8)
    Wt[(size_t)(oc0 + i) * R + out_c] = (_Float16)tile[threadIdx.x][i];
}

// ---------------------------------------------------------------------------
// Flat cast fp32 -> fp16, float4 granularity (n must be multiple of 1024)
// ---------------------------------------------------------------------------
__global__ void cast_f32_f16_kernel(const float* __restrict__ src,
                                    _Float16* __restrict__ dst) {
  const size_t i = (size_t)blockIdx.x * 256 + threadIdx.x;
  const float4 v = ((const float4*)src)[i];
  f16x4 h;
  h[0] = (_Float16)v.x; h[1] = (_Float16)v.y;
  h[2] = (_Float16)v.z; h[3] = (_Float16)v.w;
  ((f16x4*)dst)[i] = h;
}

// ---------------------------------------------------------------------------
// GEMM: C(MxN) = A(MxK) @ Bt(NxK fp16)^T + bias, epilogue by MODE.
//   MODE 0: C = elu(acc + bias)           MODE 1: C = scale[row]*(acc + bias)
// AHALF:  A is fp16 (staged via global_load_lds) vs fp32 (cvt in-kernel).
// OUTHALF: C stored as fp16 vs fp32.
// 128x128 tile, BK=64, 256 thr (4 waves 2x2), 16x16x32 f16 MFMA.
// LDS layout (XOR swizzle, global_load_lds-compatible): tile row n, k-chunk
// kc (8 halves) lives at 16B slot  n*8 + (kc ^ (n&7))  -> ds_read_b128
// fragment reads spread over all 8 bank groups (2-way residual = free).
// ---------------------------------------------------------------------------
template <int MODE, bool AHALF, bool OUTHALF>
__global__ __launch_bounds__(256) void gemm2(
    const void* __restrict__ Av, const _Float16* __restrict__ Bt,
    const float* __restrict__ bias, const float* __restrict__ scale,
    void* __restrict__ Cv, int K, int N) {
  constexpr int BK = 64;
  __shared__ __align__(16) _Float16 As[128 * BK];
  __shared__ __align__(16) _Float16 Bs[128 * BK];

  const int tid  = threadIdx.x;
  const int lane = tid & 63;
  const int wave = tid >> 6;
  const int quad = lane >> 4;
  const int r    = lane & 15;
  const int wm   = wave >> 1;
  const int wn   = wave & 1;
  const int m0   = blockIdx.y * 128;
  const int n0   = blockIdx.x * 128;

  // Per-lane staging source offsets (element units). Slot s = wave*256+t*64+lane.
  size_t aoff[4], boff[4];
  int slot[4];
#pragma unroll
  for (int t = 0; t < 4; ++t) {
    const int s  = wave * 256 + t * 64 + lane;
    const int n  = s >> 3;
    const int kc = (s & 7) ^ (n & 7);
    aoff[t] = (size_t)(m0 + n) * K + kc * 8;
    boff[t] = (size_t)(n0 + n) * K + kc * 8;
    slot[t] = s;
  }

  f32x4 acc[4][4] = {};
  const _Float16* Ah = (const _Float16*)Av;
  const float*    Af = (const float*)Av;

  for (int k0 = 0; k0 < K; k0 += BK) {
    __syncthreads();
    if (AHALF) {
#pragma unroll
      for (int t = 0; t < 4; ++t)
        __builtin_amdgcn_global_load_lds(GPTR(Ah + aoff[t] + k0),
                                         SPTR(As + (wave * 256 + t * 64) * 8),
                                         16, 0, 0);
    } else {
#pragma unroll
      for (int t = 0; t < 4; ++t) {
        const float* ap = Af + aoff[t] + k0;
        const float4 v0 = *(const float4*)ap;
        const float4 v1 = *(const float4*)(ap + 4);
        f16x8 h;
        h[0] = (_Float16)v0.x; h[1] = (_Float16)v0.y;
        h[2] = (_Float16)v0.z; h[3] = (_Float16)v0.w;
        h[4] = (_Float16)v1.x; h[5] = (_Float16)v1.y;
        h[6] = (_Float16)v1.z; h[7] = (_Float16)v1.w;
        *(f16x8*)(As + (size_t)slot[t] * 8) = h;
      }
    }
#pragma unroll
    for (int t = 0; t < 4; ++t)
      __builtin_amdgcn_global_load_lds(GPTR(Bt + boff[t] + k0),
                                       SPTR(Bs + (wave * 256 + t * 64) * 8),
                                       16, 0, 0);
    __syncthreads();

#pragma unroll
    for (int ki = 0; ki < 2; ++ki) {
      f16x8 af[4], bf[4];
#pragma unroll
      for (int i = 0; i < 4; ++i) {
        const int an = wm * 64 + i * 16 + r;
        af[i] = *(const f16x8*)(As + (an * 8 + ((ki * 4 + quad) ^ (an & 7))) * 8);
      }
#pragma unroll
      for (int j = 0; j < 4; ++j) {
        const int bn = wn * 64 + j * 16 + r;
        bf[j] = *(const f16x8*)(Bs + (bn * 8 + ((ki * 4 + quad) ^ (bn & 7))) * 8);
      }
#pragma unroll
      for (int i = 0; i < 4; ++i)
#pragma unroll
        for (int j = 0; j < 4; ++j)
          acc[i][j] = __builtin_amdgcn_mfma_f32_16x16x32_f16(af[i], bf[j],
                                                             acc[i][j], 0, 0, 0);
    }
  }

  // Epilogue: C/D layout col=lane&15, row=quad*4+reg.
  float*    Cf = (float*)Cv;
  _Float16* Ch = (_Float16*)Cv;
#pragma unroll
  for (int i = 0; i < 4; ++i) {
#pragma unroll
    for (int j = 0; j < 4; ++j) {
      const int col = n0 + wn * 64 + j * 16 + r;
      const float b = bias[col];
#pragma unroll
      for (int reg = 0; reg < 4; ++reg) {
        const int row = m0 + wm * 64 + i * 16 + quad * 4 + reg;
        float v = acc[i][j][reg] + b;
        if (MODE == 0) v = v > 0.f ? v : (expf(v) - 1.f);  // ELU (no +1)
        else           v = v * scale[row];
        if (OUTHALF) Ch[(size_t)row * N + col] = (_Float16)v;
        else         Cf[(size_t)row * N + col] = v;
      }
    }
  }
}

// ---------------------------------------------------------------------------
// scale[b] = (Qf[b].Kf[b]) / (sum(Qf[b]) * sum(Kf[b]) + eps), F = 1024.
// ---------------------------------------------------------------------------
template <bool HALF>
__global__ void reduce_scale2(const void* __restrict__ Qf,
                              const void* __restrict__ Kf,
                              float* __restrict__ scale) {
  const int b = blockIdx.x;
  const int t = threadIdx.x;
  float q[4], k[4];
  if (HALF) {
    const f16x4 qh = ((const f16x4*)((const _Float16*)Qf + (size_t)b * 1024))[t];
    const f16x4 kh = ((const f16x4*)((const _Float16*)Kf + (size_t)b * 1024))[t];
#pragma unroll
    for (int i = 0; i < 4; ++i) { q[i] = (float)qh[i]; k[i] = (float)kh[i]; }
  } else {
    const float4 qv = ((const float4*)((const float*)Qf + (size_t)b * 1024))[t];
    const float4 kv = ((const float4*)((const float*)Kf + (size_t)b * 1024))[t];
    q[0] = qv.x; q[1] = qv.y; q[2] = qv.z; q[3] = qv.w;
    k[0] = kv.x; k[1] = kv.y; k[2] = kv.z; k[3] = kv.w;
  }
  float qk = q[0] * k[0] + q[1] * k[1] + q[2] * k[2] + q[3] * k[3];
  float sq = q[0] + q[1] + q[2] + q[3];
  float sk = k[0] + k[1] + k[2] + k[3];
#pragma unroll
  for (int off = 32; off > 0; off >>= 1) {
    qk += __shfl_down(qk, off, 64);
    sq += __shfl_down(sq, off, 64);
    sk += __shfl_down(sk, off, 64);
  }
  __shared__ float buf[3][4];
  const int lane = t & 63, wv = t >> 6;
  if (lane == 0) { buf[0][wv] = qk; buf[1][wv] = sq; buf[2][wv] = sk; }
  __syncthreads();
  if (t == 0) {
    const float QK = buf[0][0] + buf[0][1] + buf[0][2] + buf[0][3];
    const float SQ = buf[1][0] + buf[1][1] + buf[1][2] + buf[1][3];
    const float SK = buf[2][0] + buf[2][1] + buf[2][2] + buf[2][3];
    scale[b] = QK / (SQ * SK + 1e-6f);
  }
}

// ---------------------------------------------------------------------------
extern "C" void kernel_launch(void* const* d_in, const int* in_sizes, int n_in,
                              void* d_out, int out_size, void* d_ws,
                              size_t ws_size, hipStream_t stream) {
  const float* Q  = (const float*)d_in[0];
  const float* K_ = (const float*)d_in[1];
  const float* V  = (const float*)d_in[2];
  const float* Wq = (const float*)d_in[3];
  const float* bq = (const float*)d_in[4];
  const float* Wk = (const float*)d_in[5];
  const float* bk = (const float*)d_in[6];
  const float* Wv = (const float*)d_in[7];
  const float* bv = (const float*)d_in[8];
  float* out = (float*)d_out;

  const int B = 8192, D = 2048, F = 1024;
  const size_t MiB = 1u << 20;
  char* ws = (char*)d_ws;

  // Fast path ws layout:
  //   [0, 8M):    WqT(4M)+WkT(4M); later WvT(8M) overwrites (after feat GEMMs)
  //   [8M, 40M):  QfH(16M)+KfH(16M); later Vh(32M) overwrites (after reduce)
  //   [40M, +32K): scale
  const size_t NEED_FAST = 40 * MiB + 64 * 1024;

  if (ws_size >= NEED_FAST) {
    _Float16* WqT = (_Float16*)ws;
    _Float16* WkT = (_Float16*)(ws + 4 * MiB);
    _Float16* WvT = (_Float16*)ws;             // reuses weight region
    _Float16* QfH = (_Float16*)(ws + 8 * MiB);
    _Float16* KfH = (_Float16*)(ws + 24 * MiB);
    _Float16* Vh  = (_Float16*)(ws + 8 * MiB); // reuses feature region
    float* scale  = (float*)(ws + 40 * MiB);
    _Float16* Qh = (_Float16*)d_out;                     // d_out as fp16 scratch
    _Float16* Kh = (_Float16*)d_out + (size_t)B * D;     // exactly fills d_out

    dim3 tb(32, 8);
    transpose_cast_kernel<<<dim3(F / 32, D / 32), tb, 0, stream>>>(Wq, WqT, D, F);
    transpose_cast_kernel<<<dim3(F / 32, D / 32), tb, 0, stream>>>(Wk, WkT, D, F);
    const int castBlocks = (B * D / 4) / 256;  // 16384
    cast_f32_f16_kernel<<<castBlocks, 256, 0, stream>>>(Q,  Qh);
    cast_f32_f16_kernel<<<castBlocks, 256, 0, stream>>>(K_, Kh);

    gemm2<0, true, true><<<dim3(F / 128, B / 128), 256, 0, stream>>>(
        Qh, WqT, bq, nullptr, QfH, D, F);
    gemm2<0, true, true><<<dim3(F / 128, B / 128), 256, 0, stream>>>(
        Kh, WkT, bk, nullptr, KfH, D, F);
    reduce_scale2<true><<<B, 256, 0, stream>>>(QfH, KfH, scale);

    cast_f32_f16_kernel<<<castBlocks, 256, 0, stream>>>(V, Vh);
    transpose_cast_kernel<<<dim3(D / 32, D / 32), tb, 0, stream>>>(Wv, WvT, D, D);
    gemm2<1, true, false><<<dim3(D / 128, B / 128), 256, 0, stream>>>(
        Vh, WvT, bv, scale, out, D, D);
  } else {
    // Fallback (round-1 memory plan, improved GEMM): fp32 A staging in-kernel.
    _Float16* WqT = (_Float16*)ws;
    _Float16* WkT = (_Float16*)(ws + 4 * MiB);
    _Float16* WvT = (_Float16*)(ws + 8 * MiB);
    float* scale  = (float*)(ws + 16 * MiB);
    float* Qf = out;
    float* Kf = out + (size_t)B * F;

    dim3 tb(32, 8);
    transpose_cast_kernel<<<dim3(F / 32, D / 32), tb, 0, stream>>>(Wq, WqT, D, F);
    transpose_cast_kernel<<<dim3(F / 32, D / 32), tb, 0, stream>>>(Wk, WkT, D, F);
    transpose_cast_kernel<<<dim3(D / 32, D / 32), tb, 0, stream>>>(Wv, WvT, D, D);

    gemm2<0, false, false><<<dim3(F / 128, B / 128), 256, 0, stream>>>(
        Q, WqT, bq, nullptr, Qf, D, F);
    gemm2<0, false, false><<<dim3(F / 128, B / 128), 256, 0, stream>>>(
        K_, WkT, bk, nullptr, Kf, D, F);
    reduce_scale2<false><<<B, 256, 0, stream>>>(Qf, Kf, scale);
    gemm2<1, false, false><<<dim3(D / 128, B / 128), 256, 0, stream>>>(
        V, WvT, bv, scale, out, D, D);
  }
}

// Round 3
// 440.809 us; speedup vs baseline: 1.2714x; 1.0007x over previous
//
#include <hip/hip_runtime.h>
#include <hip/hip_fp16.h>
#include <cstdint>
#include <cstddef>

typedef _Float16 f16x8 __attribute__((ext_vector_type(8)));
typedef _Float16 f16x4 __attribute__((ext_vector_type(4)));
typedef float    f32x4 __attribute__((ext_vector_type(4)));

#define GPTR(p) ((const __attribute__((address_space(1))) void*)(p))
#define SPTR(p) ((__attribute__((address_space(3))) void*)(p))

// ---------------------------------------------------------------------------
// Transpose + cast fp32 -> fp16 : W (R x C) row-major -> Wt (C x R) row-major
// ---------------------------------------------------------------------------
__global__ void transpose_cast_kernel(const float* __restrict__ W,
                                      _Float16* __restrict__ Wt,
                                      int R, int C) {
  __shared__ float tile[32][33];
  const int c  = blockIdx.x * 32 + threadIdx.x;
  const int r0 = blockIdx.y * 32;
  for (int i = threadIdx.y; i < 32; i += 8)
    tile[i][threadIdx.x] = W[(size_t)(r0 + i) * C + c];
  __syncthreads();
  const int out_c = r0 + threadIdx.x;   // new col = old row
  const int oc0   = blockIdx.x * 32;    // new row = old col
  for (int i = threadIdx.y; i < 32; i += 8)
    Wt[(size_t)(oc0 + i) * R + out_c] = (_Float16)tile[threadIdx.x][i];
}

// ---------------------------------------------------------------------------
// Flat cast fp32 -> fp16, float4 granularity
// ---------------------------------------------------------------------------
__global__ void cast_f32_f16_kernel(const float* __restrict__ src,
                                    _Float16* __restrict__ dst) {
  const size_t i = (size_t)blockIdx.x * 256 + threadIdx.x;
  const float4 v = ((const float4*)src)[i];
  f16x4 h;
  h[0] = (_Float16)v.x; h[1] = (_Float16)v.y;
  h[2] = (_Float16)v.z; h[3] = (_Float16)v.w;
  ((f16x4*)dst)[i] = h;
}

// ---------------------------------------------------------------------------
// GEMM: C(MxN) = A(MxK) @ Bt(NxK fp16)^T + bias, epilogue by MODE.
//   MODE 0: C = elu(acc + bias)           MODE 1: C = scale[row]*(acc + bias)
// Per-block B/bias select at row msplit enables stacking two GEMMs along M
// (feature maps: rows < 8192 use Wq/bq, rows >= 8192 use Wk/bk) so the
// stacked launch reaches 1024 blocks = 4 blocks/CU (vs 512 = 2/CU, which
// measured 362 TF vs 694 TF in round 2).
// AHALF:  A is fp16 (staged via global_load_lds) vs fp32 (cvt in-kernel).
// OUTHALF: C stored as fp16 vs fp32.
// 128x128 tile, BK=64, 256 thr (4 waves 2x2), 16x16x32 f16 MFMA.
// LDS layout (XOR swizzle, global_load_lds-compatible): tile row n, k-chunk
// kc (8 halves) lives at 16B slot  n*8 + (kc ^ (n&7))  -> conflict-free
// (SQ_LDS_BANK_CONFLICT == 0 measured in round 2).
// ---------------------------------------------------------------------------
template <int MODE, bool AHALF, bool OUTHALF>
__global__ __launch_bounds__(256) void gemm2(
    const void* __restrict__ Av,
    const _Float16* __restrict__ Bt0, const _Float16* __restrict__ Bt1,
    const float* __restrict__ bias0, const float* __restrict__ bias1,
    int msplit, const float* __restrict__ scale,
    void* __restrict__ Cv, int K, int N) {
  constexpr int BK = 64;
  __shared__ __align__(16) _Float16 As[128 * BK];
  __shared__ __align__(16) _Float16 Bs[128 * BK];

  const int tid  = threadIdx.x;
  const int lane = tid & 63;
  const int wave = tid >> 6;
  const int quad = lane >> 4;
  const int r    = lane & 15;
  const int wm   = wave >> 1;
  const int wn   = wave & 1;
  const int m0   = blockIdx.y * 128;
  const int n0   = blockIdx.x * 128;

  const _Float16* Bt  = (m0 >= msplit) ? Bt1 : Bt0;
  const float* bias   = (m0 >= msplit) ? bias1 : bias0;

  // Per-lane staging source offsets (element units). Slot s = wave*256+t*64+lane.
  size_t aoff[4], boff[4];
  int slot[4];
#pragma unroll
  for (int t = 0; t < 4; ++t) {
    const int s  = wave * 256 + t * 64 + lane;
    const int n  = s >> 3;
    const int kc = (s & 7) ^ (n & 7);
    aoff[t] = (size_t)(m0 + n) * K + kc * 8;
    boff[t] = (size_t)(n0 + n) * K + kc * 8;
    slot[t] = s;
  }

  f32x4 acc[4][4] = {};
  const _Float16* Ah = (const _Float16*)Av;
  const float*    Af = (const float*)Av;

  for (int k0 = 0; k0 < K; k0 += BK) {
    __syncthreads();
    if (AHALF) {
#pragma unroll
      for (int t = 0; t < 4; ++t)
        __builtin_amdgcn_global_load_lds(GPTR(Ah + aoff[t] + k0),
                                         SPTR(As + (wave * 256 + t * 64) * 8),
                                         16, 0, 0);
    } else {
#pragma unroll
      for (int t = 0; t < 4; ++t) {
        const float* ap = Af + aoff[t] + k0;
        const float4 v0 = *(const float4*)ap;
        const float4 v1 = *(const float4*)(ap + 4);
        f16x8 h;
        h[0] = (_Float16)v0.x; h[1] = (_Float16)v0.y;
        h[2] = (_Float16)v0.z; h[3] = (_Float16)v0.w;
        h[4] = (_Float16)v1.x; h[5] = (_Float16)v1.y;
        h[6] = (_Float16)v1.z; h[7] = (_Float16)v1.w;
        *(f16x8*)(As + (size_t)slot[t] * 8) = h;
      }
    }
#pragma unroll
    for (int t = 0; t < 4; ++t)
      __builtin_amdgcn_global_load_lds(GPTR(Bt + boff[t] + k0),
                                       SPTR(Bs + (wave * 256 + t * 64) * 8),
                                       16, 0, 0);
    __syncthreads();

#pragma unroll
    for (int ki = 0; ki < 2; ++ki) {
      f16x8 af[4], bf[4];
#pragma unroll
      for (int i = 0; i < 4; ++i) {
        const int an = wm * 64 + i * 16 + r;
        af[i] = *(const f16x8*)(As + (an * 8 + ((ki * 4 + quad) ^ (an & 7))) * 8);
      }
#pragma unroll
      for (int j = 0; j < 4; ++j) {
        const int bn = wn * 64 + j * 16 + r;
        bf[j] = *(const f16x8*)(Bs + (bn * 8 + ((ki * 4 + quad) ^ (bn & 7))) * 8);
      }
#pragma unroll
      for (int i = 0; i < 4; ++i)
#pragma unroll
        for (int j = 0; j < 4; ++j)
          acc[i][j] = __builtin_amdgcn_mfma_f32_16x16x32_f16(af[i], bf[j],
                                                             acc[i][j], 0, 0, 0);
    }
  }

  // Epilogue: C/D layout col=lane&15, row=quad*4+reg.
  float*    Cf = (float*)Cv;
  _Float16* Ch = (_Float16*)Cv;
#pragma unroll
  for (int i = 0; i < 4; ++i) {
#pragma unroll
    for (int j = 0; j < 4; ++j) {
      const int col = n0 + wn * 64 + j * 16 + r;
      const float b = bias[col];
#pragma unroll
      for (int reg = 0; reg < 4; ++reg) {
        const int row = m0 + wm * 64 + i * 16 + quad * 4 + reg;
        float v = acc[i][j][reg] + b;
        if (MODE == 0) v = v > 0.f ? v : (expf(v) - 1.f);  // ELU (no +1)
        else           v = v * scale[row];
        if (OUTHALF) Ch[(size_t)row * N + col] = (_Float16)v;
        else         Cf[(size_t)row * N + col] = v;
      }
    }
  }
}

// ---------------------------------------------------------------------------
// scale[b] = (Qf[b].Kf[b]) / (sum(Qf[b]) * sum(Kf[b]) + eps), F = 1024.
// ---------------------------------------------------------------------------
template <bool HALF>
__global__ void reduce_scale2(const void* __restrict__ Qf,
                              const void* __restrict__ Kf,
                              float* __restrict__ scale) {
  const int b = blockIdx.x;
  const int t = threadIdx.x;
  float q[4], k[4];
  if (HALF) {
    const f16x4 qh = ((const f16x4*)((const _Float16*)Qf + (size_t)b * 1024))[t];
    const f16x4 kh = ((const f16x4*)((const _Float16*)Kf + (size_t)b * 1024))[t];
#pragma unroll
    for (int i = 0; i < 4; ++i) { q[i] = (float)qh[i]; k[i] = (float)kh[i]; }
  } else {
    const float4 qv = ((const float4*)((const float*)Qf + (size_t)b * 1024))[t];
    const float4 kv = ((const float4*)((const float*)Kf + (size_t)b * 1024))[t];
    q[0] = qv.x; q[1] = qv.y; q[2] = qv.z; q[3] = qv.w;
    k[0] = kv.x; k[1] = kv.y; k[2] = kv.z; k[3] = kv.w;
  }
  float qk = q[0] * k[0] + q[1] * k[1] + q[2] * k[2] + q[3] * k[3];
  float sq = q[0] + q[1] + q[2] + q[3];
  float sk = k[0] + k[1] + k[2] + k[3];
#pragma unroll
  for (int off = 32; off > 0; off >>= 1) {
    qk += __shfl_down(qk, off, 64);
    sq += __shfl_down(sq, off, 64);
    sk += __shfl_down(sk, off, 64);
  }
  __shared__ float buf[3][4];
  const int lane = t & 63, wv = t >> 6;
  if (lane == 0) { buf[0][wv] = qk; buf[1][wv] = sq; buf[2][wv] = sk; }
  __syncthreads();
  if (t == 0) {
    const float QK = buf[0][0] + buf[0][1] + buf[0][2] + buf[0][3];
    const float SQ = buf[1][0] + buf[1][1] + buf[1][2] + buf[1][3];
    const float SK = buf[2][0] + buf[2][1] + buf[2][2] + buf[2][3];
    scale[b] = QK / (SQ * SK + 1e-6f);
  }
}

// ---------------------------------------------------------------------------
extern "C" void kernel_launch(void* const* d_in, const int* in_sizes, int n_in,
                              void* d_out, int out_size, void* d_ws,
                              size_t ws_size, hipStream_t stream) {
  const float* Q  = (const float*)d_in[0];
  const float* K_ = (const float*)d_in[1];
  const float* V  = (const float*)d_in[2];
  const float* Wq = (const float*)d_in[3];
  const float* bq = (const float*)d_in[4];
  const float* Wk = (const float*)d_in[5];
  const float* bk = (const float*)d_in[6];
  const float* Wv = (const float*)d_in[7];
  const float* bv = (const float*)d_in[8];
  float* out = (float*)d_out;

  const int B = 8192, D = 2048, F = 1024;
  const size_t MiB = 1u << 20;
  char* ws = (char*)d_ws;

  // Fast path ws layout:
  //   [0, 8M):    WqT(4M)+WkT(4M); later WvT(8M) overwrites (after feat GEMM)
  //   [8M, 40M):  QfH(16M)+KfH(16M) contiguous; later Vh(32M) overwrites
  //   [40M, +32K): scale
  const size_t NEED_FAST = 40 * MiB + 64 * 1024;

  if (ws_size >= NEED_FAST) {
    _Float16* WqT = (_Float16*)ws;
    _Float16* WkT = (_Float16*)(ws + 4 * MiB);
    _Float16* WvT = (_Float16*)ws;             // reuses weight region
    _Float16* QfH = (_Float16*)(ws + 8 * MiB);
    _Float16* KfH = (_Float16*)(ws + 24 * MiB);
    _Float16* Vh  = (_Float16*)(ws + 8 * MiB); // reuses feature region
    float* scale  = (float*)(ws + 40 * MiB);
    _Float16* Qh = (_Float16*)d_out;                  // d_out as fp16 scratch
    _Float16* Kh = (_Float16*)d_out + (size_t)B * D;  // adjacent -> stacked M

    dim3 tb(32, 8);
    transpose_cast_kernel<<<dim3(F / 32, D / 32), tb, 0, stream>>>(Wq, WqT, D, F);
    transpose_cast_kernel<<<dim3(F / 32, D / 32), tb, 0, stream>>>(Wk, WkT, D, F);
    const int castBlocks = (B * D / 4) / 256;  // 16384
    cast_f32_f16_kernel<<<castBlocks, 256, 0, stream>>>(Q,  Qh);
    cast_f32_f16_kernel<<<castBlocks, 256, 0, stream>>>(K_, Kh);

    // Stacked feature GEMM: M = 16384 ([Qh;Kh]), split at 8192 selects
    // Wq/bq vs Wk/bk. Output QfH/KfH contiguous. Grid 8x128 = 1024 blocks.
    gemm2<0, true, true><<<dim3(F / 128, (2 * B) / 128), 256, 0, stream>>>(
        Qh, WqT, WkT, bq, bk, B, nullptr, QfH, D, F);
    reduce_scale2<true><<<B, 256, 0, stream>>>(QfH, KfH, scale);

    cast_f32_f16_kernel<<<castBlocks, 256, 0, stream>>>(V, Vh);
    transpose_cast_kernel<<<dim3(D / 32, D / 32), tb, 0, stream>>>(Wv, WvT, D, D);
    gemm2<1, true, false><<<dim3(D / 128, B / 128), 256, 0, stream>>>(
        Vh, WvT, WvT, bv, bv, 1 << 30, scale, out, D, D);
  } else {
    // Fallback: fp32 A staging in-kernel, Qf/Kf fp32 in d_out.
    _Float16* WqT = (_Float16*)ws;
    _Float16* WkT = (_Float16*)(ws + 4 * MiB);
    _Float16* WvT = (_Float16*)(ws + 8 * MiB);
    float* scale  = (float*)(ws + 16 * MiB);
    float* Qf = out;
    float* Kf = out + (size_t)B * F;

    dim3 tb(32, 8);
    transpose_cast_kernel<<<dim3(F / 32, D / 32), tb, 0, stream>>>(Wq, WqT, D, F);
    transpose_cast_kernel<<<dim3(F / 32, D / 32), tb, 0, stream>>>(Wk, WkT, D, F);
    transpose_cast_kernel<<<dim3(D / 32, D / 32), tb, 0, stream>>>(Wv, WvT, D, D);

    gemm2<0, false, false><<<dim3(F / 128, B / 128), 256, 0, stream>>>(
        Q, WqT, WqT, bq, bq, 1 << 30, nullptr, Qf, D, F);
    gemm2<0, false, false><<<dim3(F / 128, B / 128), 256, 0, stream>>>(
        K_, WkT, WkT, bk, bk, 1 << 30, nullptr, Kf, D, F);
    reduce_scale2<false><<<B, 256, 0, stream>>>(Qf, Kf, scale);
    gemm2<1, false, false><<<dim3(D / 128, B / 128), 256, 0, stream>>>(
        V, WvT, WvT, bv, bv, 1 << 30, scale, out, D, D);
  }
}